// Round 1
// baseline (193.440 us; speedup 1.0000x reference)
//
#include <hip/hip_runtime.h>
#include <hip/hip_bf16.h>
#include <stdint.h>

// Problem constants: B=2, T=2048, C=1024, H=16, D=64
#define TT 2048
#define CC 1024
#define NH 16
#define HD 64
#define BT 4096          // B*T rows

typedef float f32x4 __attribute__((ext_vector_type(4)));
typedef __bf16 bf16x8 __attribute__((ext_vector_type(8)));
typedef __bf16 bf16x4 __attribute__((ext_vector_type(4)));

#define MFMA(a, b, c) __builtin_amdgcn_mfma_f32_16x16x32_bf16((a), (b), (c), 0, 0, 0)

__device__ __forceinline__ void gload16(const void* g, void* l) {
    __builtin_amdgcn_global_load_lds(
        (const __attribute__((address_space(1))) void*)g,
        (__attribute__((address_space(3))) void*)l,
        16, 0, 0);
}

// ---------------- fp32 -> bf16 convert (no transpose) ----------------
__global__ __launch_bounds__(256) void conv_f32_bf16(
    const float* __restrict__ in, __bf16* __restrict__ out, int n4) {
    int i = blockIdx.x * blockDim.x + threadIdx.x;
    int stride = gridDim.x * blockDim.x;
    for (; i < n4; i += stride) {
        float4 v = reinterpret_cast<const float4*>(in)[i];
        bf16x4 o;
        o.x = (__bf16)v.x; o.y = (__bf16)v.y; o.z = (__bf16)v.z; o.w = (__bf16)v.w;
        reinterpret_cast<bf16x4*>(out)[i] = o;
    }
}

// ---------------- fp32 [R][C] -> bf16 [C][R] transpose ----------------
__global__ __launch_bounds__(256) void transpose_f32_bf16(
    const float* __restrict__ in, __bf16* __restrict__ out, int R, int C) {
    __shared__ float tile[32][33];
    int c0 = blockIdx.x * 32, r0 = blockIdx.y * 32;
    int tx = threadIdx.x, ty = threadIdx.y;
#pragma unroll
    for (int j = 0; j < 32; j += 8)
        tile[ty + j][tx] = in[(size_t)(r0 + ty + j) * C + c0 + tx];
    __syncthreads();
#pragma unroll
    for (int j = 0; j < 32; j += 8)
        out[(size_t)(c0 + ty + j) * R + r0 + tx] = (__bf16)tile[tx][ty + j];
}

// ---------------- bf16 MFMA GEMM, 128x128 tile, BK=64 (m97 structure) ----
// C = A[M,K] * Bt[N,K]^T + bias. MODE 0: scatter to q/k/v [B,H,T,D] bf16
// (q scaled by 0.125). MODE 1: fp32 output [M,N].
template <int MODE>
__global__ __launch_bounds__(256) void gemm128(
    const __bf16* __restrict__ A, const __bf16* __restrict__ Bt,
    const float* __restrict__ bias,
    __bf16* __restrict__ oq, __bf16* __restrict__ ok, __bf16* __restrict__ ov,
    float* __restrict__ of, int M, int N, int K) {
    __shared__ __align__(16) __bf16 As[128 * 64];
    __shared__ __align__(16) __bf16 Bs[128 * 64];
    const int tid = threadIdx.x;
    const int w = tid >> 6, lane = tid & 63;
    const int l15 = lane & 15, lg = lane >> 4;
    const int m0 = blockIdx.y * 128, n0 = blockIdx.x * 128;
    const int wr = w >> 1, wc = w & 1;

    const f32x4 zero4 = {0.f, 0.f, 0.f, 0.f};
    f32x4 acc[4][4];
#pragma unroll
    for (int m = 0; m < 4; ++m)
#pragma unroll
        for (int n = 0; n < 4; ++n) acc[m][n] = zero4;

    const char* Ab = (const char*)A;
    const char* Bb = (const char*)Bt;
    const size_t rowbytes = (size_t)K * 2;

    for (int kt = 0; kt < K; kt += 64) {
#pragma unroll
        for (int j = 0; j < 4; ++j) {
            int base = (w * 4 + j) * 1024;      // byte offset of this wave-call in tile
            int d0 = base + lane * 16;          // linear LDS dest byte for this lane
            int row = d0 >> 7;                  // 128B per row (64 bf16)
            int colb = d0 & 127;
            int scolb = colb ^ ((row & 7) << 4);  // pre-swizzled source (T2, m173)
            gload16(Ab + (size_t)(m0 + row) * rowbytes + (size_t)kt * 2 + scolb,
                    (char*)As + base);
            gload16(Bb + (size_t)(n0 + row) * rowbytes + (size_t)kt * 2 + scolb,
                    (char*)Bs + base);
        }
        __syncthreads();
#pragma unroll
        for (int kk = 0; kk < 2; ++kk) {
            bf16x8 af[4], bfr[4];
#pragma unroll
            for (int m = 0; m < 4; ++m) {
                int row = wr * 64 + m * 16 + l15;
                int colb = kk * 64 + lg * 16;
                af[m] = *(const bf16x8*)((const char*)As + row * 128 +
                                         (colb ^ ((row & 7) << 4)));
            }
#pragma unroll
            for (int n = 0; n < 4; ++n) {
                int row = wc * 64 + n * 16 + l15;
                int colb = kk * 64 + lg * 16;
                bfr[n] = *(const bf16x8*)((const char*)Bs + row * 128 +
                                          (colb ^ ((row & 7) << 4)));
            }
#pragma unroll
            for (int m = 0; m < 4; ++m)
#pragma unroll
                for (int n = 0; n < 4; ++n)
                    acc[m][n] = MFMA(af[m], bfr[n], acc[m][n]);
        }
        __syncthreads();
    }

    // epilogue. D layout: col = lane&15, row = (lane>>4)*4 + r  [verified m89/m91]
#pragma unroll
    for (int n = 0; n < 4; ++n) {
        int col = n0 + wc * 64 + n * 16 + l15;
        float bs = bias[col];
        if constexpr (MODE == 0) {
            int sec = col >> 10;          // 0=q 1=k 2=v (uniform within fragment)
            int cc = col & 1023;
            int h = cc >> 6, d = cc & 63;
            __bf16* dst = (sec == 0) ? oq : (sec == 1) ? ok : ov;
            float mult = (sec == 0) ? 0.125f : 1.0f;  // fold softmax scale into q
#pragma unroll
            for (int m = 0; m < 4; ++m) {
                int rowb = m0 + wr * 64 + m * 16 + lg * 4;
#pragma unroll
                for (int r = 0; r < 4; ++r) {
                    int row = rowb + r;                // = b*2048 + t
                    int bb = row >> 11, t = row & 2047;
                    float val = (acc[m][n][r] + bs) * mult;
                    dst[((size_t)(bb * NH + h) * TT + t) * HD + d] = (__bf16)val;
                }
            }
        } else {
#pragma unroll
            for (int m = 0; m < 4; ++m) {
                int rowb = m0 + wr * 64 + m * 16 + lg * 4;
#pragma unroll
                for (int r = 0; r < 4; ++r) {
                    int row = rowb + r;
                    of[(size_t)row * N + col] = acc[m][n][r] + bs;
                }
            }
        }
    }
}

// ---------------- causal flash attention ----------------
// q,k,v: [B*H][T][64] bf16 (q pre-scaled by 0.125). y: [B*T][1024] bf16.
// Block: 128 q rows (4 waves x 32), K-tiles of 64.
__global__ __launch_bounds__(256) void attn_kernel(
    const __bf16* __restrict__ q, const __bf16* __restrict__ k,
    const __bf16* __restrict__ v, __bf16* __restrict__ y) {
    __shared__ __align__(16) __bf16 Klds[64 * 64];       // [k][d] linear + XOR swz
    __shared__ __align__(16) __bf16 Vt[64 * 72];         // [d][k] padded
    __shared__ __align__(16) __bf16 Plds[4][32 * 72];    // per-wave [q][k] padded

    const int bh = blockIdx.y;
    const int qi = (gridDim.x - 1) - blockIdx.x;   // heavy tiles first
    const int qb0 = qi * 128;
    const int tid = threadIdx.x, w = tid >> 6, lane = tid & 63;
    const int l15 = lane & 15, lg = lane >> 4;
    const int qbw = qb0 + w * 32;
    const __bf16* qh = q + (size_t)bh * (TT * HD);
    const __bf16* kh = k + (size_t)bh * (TT * HD);
    const __bf16* vh = v + (size_t)bh * (TT * HD);

    const f32x4 zero4 = {0.f, 0.f, 0.f, 0.f};

    bf16x8 qf[2][2];
#pragma unroll
    for (int a = 0; a < 2; ++a)
#pragma unroll
        for (int kk = 0; kk < 2; ++kk)
            qf[a][kk] = *(const bf16x8*)&qh[(size_t)(qbw + a * 16 + l15) * HD +
                                           kk * 32 + lg * 8];

    float mrun[2][4], lrun[2][4];
    f32x4 oacc[2][4];
#pragma unroll
    for (int a = 0; a < 2; ++a)
#pragma unroll
        for (int r = 0; r < 4; ++r) { mrun[a][r] = -1e30f; lrun[a][r] = 0.f; }
#pragma unroll
    for (int a = 0; a < 2; ++a)
#pragma unroll
        for (int f = 0; f < 4; ++f) oacc[a][f] = zero4;

    const int nkt = qb0 / 64 + 2;
    for (int ti = 0; ti < nkt; ++ti) {
        const int kb = ti * 64;
        // stage K via global_load_lds (linear dest, pre-swizzled source)
#pragma unroll
        for (int j = 0; j < 2; ++j) {
            int base = (w * 2 + j) * 1024;
            int d0 = base + lane * 16;
            int row = d0 >> 7, colb = d0 & 127;
            int scolb = colb ^ ((row & 7) << 4);
            gload16((const char*)kh + (size_t)(kb + row) * 128 + scolb,
                    (char*)Klds + base);
        }
        // stage V transposed: kr = lane (2-way LDS write conflicts only)
#pragma unroll
        for (int j = 0; j < 2; ++j) {
            int c8 = w + 4 * j;
            bf16x8 vv = *(const bf16x8*)&vh[(size_t)(kb + lane) * HD + c8 * 8];
#pragma unroll
            for (int e = 0; e < 8; ++e)
                Vt[(c8 * 8 + e) * 72 + lane] = vv[e];
        }
        __syncthreads();

        if (kb <= qbw + 31) {   // wave-uniform: skip fully-masked tiles
            // S = Q K^T  (S frag: col=k=lane&15, row=q=(lane>>4)*4+r)
            f32x4 s[2][4];
#pragma unroll
            for (int a = 0; a < 2; ++a)
#pragma unroll
                for (int kf = 0; kf < 4; ++kf) s[a][kf] = zero4;
#pragma unroll
            for (int kf = 0; kf < 4; ++kf) {
                int krow = kf * 16 + l15;
                bf16x8 k0 = *(const bf16x8*)((const char*)Klds + krow * 128 +
                                             ((lg * 16) ^ ((krow & 7) << 4)));
                bf16x8 k1 = *(const bf16x8*)((const char*)Klds + krow * 128 +
                                             ((64 + lg * 16) ^ ((krow & 7) << 4)));
#pragma unroll
                for (int a = 0; a < 2; ++a) {
                    s[a][kf] = MFMA(qf[a][0], k0, s[a][kf]);
                    s[a][kf] = MFMA(qf[a][1], k1, s[a][kf]);
                }
            }
            const bool domask = (kb + 63 > qbw);
#pragma unroll
            for (int a = 0; a < 2; ++a) {
                if (domask) {
#pragma unroll
                    for (int kf = 0; kf < 4; ++kf)
#pragma unroll
                        for (int r = 0; r < 4; ++r) {
                            int col = kb + kf * 16 + l15;
                            int rowq = qbw + a * 16 + lg * 4 + r;
                            if (col > rowq) s[a][kf][r] = -1e30f;
                        }
                }
                float fac[4];
#pragma unroll
                for (int r = 0; r < 4; ++r) {
                    float m_ = fmaxf(fmaxf(s[a][0][r], s[a][1][r]),
                                     fmaxf(s[a][2][r], s[a][3][r]));
#pragma unroll
                    for (int off = 1; off < 16; off <<= 1)
                        m_ = fmaxf(m_, __shfl_xor(m_, off));
                    float mn = fmaxf(mrun[a][r], m_);
                    fac[r] = __expf(mrun[a][r] - mn);
                    mrun[a][r] = mn;
                    float ss = 0.f;
#pragma unroll
                    for (int kf = 0; kf < 4; ++kf) {
                        float p = __expf(s[a][kf][r] - mn);
                        s[a][kf][r] = p;
                        ss += p;
                    }
#pragma unroll
                    for (int off = 1; off < 16; off <<= 1)
                        ss += __shfl_xor(ss, off);
                    lrun[a][r] = lrun[a][r] * fac[r] + ss;
                }
#pragma unroll
                for (int f = 0; f < 4; ++f)
#pragma unroll
                    for (int r = 0; r < 4; ++r) oacc[a][f][r] *= fac[r];
                // P -> LDS (bf16), layout [q][k]
#pragma unroll
                for (int kf = 0; kf < 4; ++kf)
#pragma unroll
                    for (int r = 0; r < 4; ++r)
                        Plds[w][(a * 16 + lg * 4 + r) * 72 + kf * 16 + l15] =
                            (__bf16)s[a][kf][r];
            }
            // O += P V   (A = P[q][k], B = Vt[d][k]; D: col=d, row=q)
#pragma unroll
            for (int a = 0; a < 2; ++a) {
                bf16x8 pa0 = *(const bf16x8*)&Plds[w][(a * 16 + l15) * 72 + lg * 8];
                bf16x8 pa1 = *(const bf16x8*)&Plds[w][(a * 16 + l15) * 72 + 32 + lg * 8];
#pragma unroll
                for (int f = 0; f < 4; ++f) {
                    bf16x8 v0 = *(const bf16x8*)&Vt[(f * 16 + l15) * 72 + lg * 8];
                    bf16x8 v1 = *(const bf16x8*)&Vt[(f * 16 + l15) * 72 + 32 + lg * 8];
                    oacc[a][f] = MFMA(pa0, v0, oacc[a][f]);
                    oacc[a][f] = MFMA(pa1, v1, oacc[a][f]);
                }
            }
        }
        __syncthreads();
    }

    const int b = bh >> 4, h = bh & 15;
#pragma unroll
    for (int a = 0; a < 2; ++a)
#pragma unroll
        for (int f = 0; f < 4; ++f)
#pragma unroll
            for (int r = 0; r < 4; ++r) {
                int t = qbw + a * 16 + lg * 4 + r;
                float val = oacc[a][f][r] / lrun[a][r];
                y[(size_t)(b * TT + t) * CC + h * 64 + f * 16 + l15] = (__bf16)val;
            }
}

extern "C" void kernel_launch(void* const* d_in, const int* in_sizes, int n_in,
                              void* d_out, int out_size, void* d_ws, size_t ws_size,
                              hipStream_t stream) {
    const float* x      = (const float*)d_in[0];
    const float* w_attn = (const float*)d_in[1];
    const float* b_attn = (const float*)d_in[2];
    const float* w_proj = (const float*)d_in[3];
    const float* b_proj = (const float*)d_in[4];
    float* out = (float*)d_out;

    char* ws = (char*)d_ws;
    size_t off = 0;
    auto alloc = [&](size_t bytes) {
        char* p = ws + off;
        off += (bytes + 255) & ~(size_t)255;
        return p;
    };
    __bf16* xb   = (__bf16*)alloc((size_t)BT * CC * 2);
    __bf16* watb = (__bf16*)alloc((size_t)3 * CC * CC * 2);
    __bf16* wptb = (__bf16*)alloc((size_t)CC * CC * 2);
    __bf16* qb   = (__bf16*)alloc((size_t)BT * CC * 2);
    __bf16* kb   = (__bf16*)alloc((size_t)BT * CC * 2);
    __bf16* vb   = (__bf16*)alloc((size_t)BT * CC * 2);
    __bf16* yb   = (__bf16*)alloc((size_t)BT * CC * 2);

    conv_f32_bf16<<<1024, 256, 0, stream>>>(x, xb, BT * CC / 4);
    transpose_f32_bf16<<<dim3(3 * CC / 32, CC / 32), dim3(32, 8), 0, stream>>>(
        w_attn, watb, CC, 3 * CC);
    transpose_f32_bf16<<<dim3(CC / 32, CC / 32), dim3(32, 8), 0, stream>>>(
        w_proj, wptb, CC, CC);

    gemm128<0><<<dim3(3 * CC / 128, BT / 128), 256, 0, stream>>>(
        xb, watb, b_attn, qb, kb, vb, nullptr, BT, 3 * CC, CC);

    attn_kernel<<<dim3(TT / 128, 2 * NH), 256, 0, stream>>>(qb, kb, vb, yb);

    gemm128<1><<<dim3(CC / 128, BT / 128), 256, 0, stream>>>(
        yb, wptb, b_proj, nullptr, nullptr, nullptr, out, BT, CC, CC);
}

// Round 2
// 145.869 us; speedup vs baseline: 1.3261x; 1.3261x over previous
//
#include <hip/hip_runtime.h>
#include <hip/hip_bf16.h>
#include <stdint.h>

// Problem constants: B=2, T=2048, C=1024, H=16, D=64
#define TT 2048
#define CC 1024
#define NH 16
#define HD 64
#define BT 4096          // B*T rows

typedef float f32x4 __attribute__((ext_vector_type(4)));
typedef __bf16 bf16x8 __attribute__((ext_vector_type(8)));
typedef __bf16 bf16x4 __attribute__((ext_vector_type(4)));

#define MFMA(a, b, c) __builtin_amdgcn_mfma_f32_16x16x32_bf16((a), (b), (c), 0, 0, 0)

__device__ __forceinline__ void gload16(const void* g, void* l) {
    __builtin_amdgcn_global_load_lds(
        (const __attribute__((address_space(1))) void*)g,
        (__attribute__((address_space(3))) void*)l,
        16, 0, 0);
}

// ---------------- fp32 -> bf16 convert (no transpose) ----------------
__global__ __launch_bounds__(256) void conv_f32_bf16(
    const float* __restrict__ in, __bf16* __restrict__ out, int n4) {
    int i = blockIdx.x * blockDim.x + threadIdx.x;
    int stride = gridDim.x * blockDim.x;
    for (; i < n4; i += stride) {
        float4 v = reinterpret_cast<const float4*>(in)[i];
        bf16x4 o;
        o.x = (__bf16)v.x; o.y = (__bf16)v.y; o.z = (__bf16)v.z; o.w = (__bf16)v.w;
        reinterpret_cast<bf16x4*>(out)[i] = o;
    }
}

// ---------------- fp32 [R][C] -> bf16 [C][R] transpose ----------------
__global__ __launch_bounds__(256) void transpose_f32_bf16(
    const float* __restrict__ in, __bf16* __restrict__ out, int R, int C) {
    __shared__ float tile[32][33];
    int c0 = blockIdx.x * 32, r0 = blockIdx.y * 32;
    int tx = threadIdx.x, ty = threadIdx.y;
#pragma unroll
    for (int j = 0; j < 32; j += 8)
        tile[ty + j][tx] = in[(size_t)(r0 + ty + j) * C + c0 + tx];
    __syncthreads();
#pragma unroll
    for (int j = 0; j < 32; j += 8)
        out[(size_t)(c0 + ty + j) * R + r0 + tx] = (__bf16)tile[tx][ty + j];
}

// ---------------- bf16 MFMA GEMM, 128x128 tile, BK=64 (m97 structure) ----
// C = A[M,K] * Bt[N,K]^T + bias. MODE 0: scatter q/k -> [B,H,T,D] bf16
// (q scaled by 0.125), v -> [B,H,D,T] bf16 (pre-transposed for attention).
// MODE 1: fp32 output [M,N].
template <int MODE>
__global__ __launch_bounds__(256) void gemm128(
    const __bf16* __restrict__ A, const __bf16* __restrict__ Bt,
    const float* __restrict__ bias,
    __bf16* __restrict__ oq, __bf16* __restrict__ ok, __bf16* __restrict__ ov,
    float* __restrict__ of, int M, int N, int K) {
    __shared__ __align__(16) __bf16 As[128 * 64];
    __shared__ __align__(16) __bf16 Bs[128 * 64];
    const int tid = threadIdx.x;
    const int w = tid >> 6, lane = tid & 63;
    const int l15 = lane & 15, lg = lane >> 4;
    const int m0 = blockIdx.y * 128, n0 = blockIdx.x * 128;
    const int wr = w >> 1, wc = w & 1;

    const f32x4 zero4 = {0.f, 0.f, 0.f, 0.f};
    f32x4 acc[4][4];
#pragma unroll
    for (int m = 0; m < 4; ++m)
#pragma unroll
        for (int n = 0; n < 4; ++n) acc[m][n] = zero4;

    const char* Ab = (const char*)A;
    const char* Bb = (const char*)Bt;
    const size_t rowbytes = (size_t)K * 2;

    for (int kt = 0; kt < K; kt += 64) {
#pragma unroll
        for (int j = 0; j < 4; ++j) {
            int base = (w * 4 + j) * 1024;
            int d0 = base + lane * 16;
            int row = d0 >> 7;
            int colb = d0 & 127;
            int scolb = colb ^ ((row & 7) << 4);
            gload16(Ab + (size_t)(m0 + row) * rowbytes + (size_t)kt * 2 + scolb,
                    (char*)As + base);
            gload16(Bb + (size_t)(n0 + row) * rowbytes + (size_t)kt * 2 + scolb,
                    (char*)Bs + base);
        }
        __syncthreads();
#pragma unroll
        for (int kk = 0; kk < 2; ++kk) {
            bf16x8 af[4], bfr[4];
#pragma unroll
            for (int m = 0; m < 4; ++m) {
                int row = wr * 64 + m * 16 + l15;
                int colb = kk * 64 + lg * 16;
                af[m] = *(const bf16x8*)((const char*)As + row * 128 +
                                         (colb ^ ((row & 7) << 4)));
            }
#pragma unroll
            for (int n = 0; n < 4; ++n) {
                int row = wc * 64 + n * 16 + l15;
                int colb = kk * 64 + lg * 16;
                bfr[n] = *(const bf16x8*)((const char*)Bs + row * 128 +
                                          (colb ^ ((row & 7) << 4)));
            }
#pragma unroll
            for (int m = 0; m < 4; ++m)
#pragma unroll
                for (int n = 0; n < 4; ++n)
                    acc[m][n] = MFMA(af[m], bfr[n], acc[m][n]);
        }
        __syncthreads();
    }

    // epilogue. D layout: col = lane&15, row = (lane>>4)*4 + r  [verified m89/m91]
#pragma unroll
    for (int n = 0; n < 4; ++n) {
        int col = n0 + wc * 64 + n * 16 + l15;
        float bs = bias[col];
        if constexpr (MODE == 0) {
            int sec = col >> 10;          // 0=q 1=k 2=v
            int cc = col & 1023;
            int h = cc >> 6, d = cc & 63;
            if (sec == 2) {
                // V transposed: [B,H,D,T], pack 4 consecutive t per store
#pragma unroll
                for (int m = 0; m < 4; ++m) {
                    int rowb = m0 + wr * 64 + m * 16 + lg * 4;
                    int bb = rowb >> 11, t = rowb & 2047;
                    bf16x4 pk;
#pragma unroll
                    for (int r = 0; r < 4; ++r) pk[r] = (__bf16)(acc[m][n][r] + bs);
                    *(bf16x4*)&ov[((size_t)(bb * NH + h) * HD + d) * TT + t] = pk;
                }
            } else {
                __bf16* dst = (sec == 0) ? oq : ok;
                float mult = (sec == 0) ? 0.125f : 1.0f;
#pragma unroll
                for (int m = 0; m < 4; ++m) {
                    int rowb = m0 + wr * 64 + m * 16 + lg * 4;
#pragma unroll
                    for (int r = 0; r < 4; ++r) {
                        int row = rowb + r;
                        int bb = row >> 11, t = row & 2047;
                        float val = (acc[m][n][r] + bs) * mult;
                        dst[((size_t)(bb * NH + h) * TT + t) * HD + d] = (__bf16)val;
                    }
                }
            }
        } else {
#pragma unroll
            for (int m = 0; m < 4; ++m) {
                int rowb = m0 + wr * 64 + m * 16 + lg * 4;
#pragma unroll
                for (int r = 0; r < 4; ++r) {
                    int row = rowb + r;
                    of[(size_t)row * N + col] = acc[m][n][r] + bs;
                }
            }
        }
    }
}

// ---------------- causal flash attention (paired q-tiles, KVBLK=128) -----
// q,k: [B,H,T,64] bf16 (q pre-scaled by 0.125). vt: [B,H,64,T] bf16.
// y: [B*T][1024] bf16. Block = 4 waves; processes q-tile qp then 15-qp
// (uniform 17 K-steps). K/V double-buffered in LDS via global_load_lds.
__global__ __launch_bounds__(256) void attn_kernel(
    const __bf16* __restrict__ q, const __bf16* __restrict__ k,
    const __bf16* __restrict__ vt, __bf16* __restrict__ y) {
    __shared__ __align__(16) __bf16 Kb[2][128 * 64];   // [kv][d] + XOR swz
    __shared__ __align__(16) __bf16 Vb[2][64 * 128];   // [d][kv] + XOR swz
    __shared__ __align__(16) __bf16 Pl[4][32 * 136];   // per-wave [q][k] padded

    const int bh = blockIdx.y;
    const int qp = blockIdx.x;                // 0..7 pair index
    const int tid = threadIdx.x, w = tid >> 6, lane = tid & 63;
    const int l15 = lane & 15, lg = lane >> 4;
    const char* kh = (const char*)(k + (size_t)bh * TT * HD);
    const char* vh = (const char*)(vt + (size_t)bh * HD * TT);
    const __bf16* qh = q + (size_t)bh * TT * HD;
    const int qtA = qp, qtB = 15 - qp;
    const int nA = qtA + 1, nB = qtB + 1, ntot = nA + nB;

    const f32x4 zero4 = {0.f, 0.f, 0.f, 0.f};
    float mrun[2][4], lrun[2][4];
    f32x4 oacc[2][4];
    bf16x8 qf[2][2];
    int qbw = 0;

    auto stage = [&](int kvb, int buf) {
#pragma unroll
        for (int j = 0; j < 4; ++j) {
            int d0 = ((w * 4 + j) * 64 + lane) * 16;
            {   // K tile: rows kv (128B each)
                int row = d0 >> 7, colb = d0 & 127;
                gload16(kh + (size_t)(kvb + row) * 128 + (colb ^ ((row & 7) << 4)),
                        (char*)Kb[buf] + d0);
            }
            {   // V^T tile: rows d (256B each), cols kv
                int row = d0 >> 8, colb = d0 & 255;
                gload16(vh + (size_t)row * (TT * 2) + (size_t)kvb * 2 +
                            (colb ^ ((row & 7) << 4)),
                        (char*)Vb[buf] + d0);
            }
        }
    };

    auto initQ = [&](int qt) {
        qbw = qt * 128 + w * 32;
#pragma unroll
        for (int a = 0; a < 2; ++a) {
#pragma unroll
            for (int kk = 0; kk < 2; ++kk)
                qf[a][kk] = *(const bf16x8*)&qh[(size_t)(qbw + a * 16 + l15) * HD +
                                               kk * 32 + lg * 8];
#pragma unroll
            for (int r = 0; r < 4; ++r) { mrun[a][r] = -1e30f; lrun[a][r] = 0.f; }
#pragma unroll
            for (int f = 0; f < 4; ++f) oacc[a][f] = zero4;
        }
    };

    auto writeO = [&]() {
        const int b = bh >> 4, h = bh & 15;
#pragma unroll
        for (int a = 0; a < 2; ++a)
#pragma unroll
            for (int f = 0; f < 4; ++f)
#pragma unroll
                for (int r = 0; r < 4; ++r) {
                    int t = qbw + a * 16 + lg * 4 + r;
                    float val = oacc[a][f][r] / lrun[a][r];
                    y[(size_t)(b * TT + t) * CC + h * 64 + f * 16 + l15] = (__bf16)val;
                }
    };

    stage(0, 0);
    initQ(qtA);
    __syncthreads();

    for (int g = 0; g < ntot; ++g) {
        const int cur = g & 1;
        if (g + 1 < ntot)
            stage((g + 1 < nA ? g + 1 : g + 1 - nA) * 128, cur ^ 1);
        const int kb = (g < nA ? g : g - nA) * 128;

        // ---- QK^T ----  (S frag: col=k=lane&15, row=q=(lane>>4)*4+r)
        f32x4 s[2][8];
#pragma unroll
        for (int a = 0; a < 2; ++a)
#pragma unroll
            for (int kf = 0; kf < 8; ++kf) s[a][kf] = zero4;
#pragma unroll
        for (int kf = 0; kf < 8; ++kf) {
            int krow = kf * 16 + l15;
            const char* kr = (const char*)Kb[cur] + krow * 128;
            bf16x8 k0 = *(const bf16x8*)(kr + ((lg * 16) ^ ((krow & 7) << 4)));
            bf16x8 k1 = *(const bf16x8*)(kr + ((64 + lg * 16) ^ ((krow & 7) << 4)));
#pragma unroll
            for (int a = 0; a < 2; ++a) {
                s[a][kf] = MFMA(qf[a][0], k0, s[a][kf]);
                s[a][kf] = MFMA(qf[a][1], k1, s[a][kf]);
            }
        }
        const bool domask = (kb + 127 > qbw);
#pragma unroll
        for (int a = 0; a < 2; ++a) {
            if (domask) {
#pragma unroll
                for (int kf = 0; kf < 8; ++kf)
#pragma unroll
                    for (int r = 0; r < 4; ++r) {
                        int col = kb + kf * 16 + l15;
                        int rowq = qbw + a * 16 + lg * 4 + r;
                        if (col > rowq) s[a][kf][r] = -1e30f;
                    }
            }
            float fac[4];
#pragma unroll
            for (int r = 0; r < 4; ++r) {
                float m_ = s[a][0][r];
#pragma unroll
                for (int kf = 1; kf < 8; ++kf) m_ = fmaxf(m_, s[a][kf][r]);
#pragma unroll
                for (int off = 1; off < 16; off <<= 1)
                    m_ = fmaxf(m_, __shfl_xor(m_, off));
                float mn = fmaxf(mrun[a][r], m_);
                fac[r] = __expf(mrun[a][r] - mn);
                mrun[a][r] = mn;
                float ss = 0.f;
#pragma unroll
                for (int kf = 0; kf < 8; ++kf) {
                    float p = __expf(s[a][kf][r] - mn);
                    s[a][kf][r] = p;
                    ss += p;
                }
#pragma unroll
                for (int off = 1; off < 16; off <<= 1)
                    ss += __shfl_xor(ss, off);
                lrun[a][r] = lrun[a][r] * fac[r] + ss;
            }
#pragma unroll
            for (int f = 0; f < 4; ++f)
#pragma unroll
                for (int r = 0; r < 4; ++r) oacc[a][f][r] *= fac[r];
#pragma unroll
            for (int kf = 0; kf < 8; ++kf)
#pragma unroll
                for (int r = 0; r < 4; ++r)
                    Pl[w][(a * 16 + lg * 4 + r) * 136 + kf * 16 + l15] =
                        (__bf16)s[a][kf][r];
        }
        // ---- O += P V ----  (A = P[q][k], B = V[k][d] from Vt[d][k] LDS)
#pragma unroll
        for (int kq = 0; kq < 4; ++kq) {
            bf16x8 pa[2];
#pragma unroll
            for (int a = 0; a < 2; ++a)
                pa[a] = *(const bf16x8*)&Pl[w][(a * 16 + l15) * 136 + kq * 32 + lg * 8];
#pragma unroll
            for (int f = 0; f < 4; ++f) {
                int vrow = f * 16 + l15;
                bf16x8 vf = *(const bf16x8*)((const char*)Vb[cur] + vrow * 256 +
                                ((kq * 64 + lg * 16) ^ ((vrow & 7) << 4)));
#pragma unroll
                for (int a = 0; a < 2; ++a)
                    oacc[a][f] = MFMA(pa[a], vf, oacc[a][f]);
            }
        }
        __syncthreads();
        if (g == nA - 1) { writeO(); initQ(qtB); }
    }
    writeO();
}

extern "C" void kernel_launch(void* const* d_in, const int* in_sizes, int n_in,
                              void* d_out, int out_size, void* d_ws, size_t ws_size,
                              hipStream_t stream) {
    const float* x      = (const float*)d_in[0];
    const float* w_attn = (const float*)d_in[1];
    const float* b_attn = (const float*)d_in[2];
    const float* w_proj = (const float*)d_in[3];
    const float* b_proj = (const float*)d_in[4];
    float* out = (float*)d_out;

    char* ws = (char*)d_ws;
    size_t off = 0;
    auto alloc = [&](size_t bytes) {
        char* p = ws + off;
        off += (bytes + 255) & ~(size_t)255;
        return p;
    };
    __bf16* xb   = (__bf16*)alloc((size_t)BT * CC * 2);
    __bf16* watb = (__bf16*)alloc((size_t)3 * CC * CC * 2);
    __bf16* wptb = (__bf16*)alloc((size_t)CC * CC * 2);
    __bf16* qb   = (__bf16*)alloc((size_t)BT * CC * 2);
    __bf16* kbuf = (__bf16*)alloc((size_t)BT * CC * 2);
    __bf16* vtb  = (__bf16*)alloc((size_t)BT * CC * 2);  // [B,H,D,T]
    __bf16* yb   = (__bf16*)alloc((size_t)BT * CC * 2);

    conv_f32_bf16<<<1024, 256, 0, stream>>>(x, xb, BT * CC / 4);
    transpose_f32_bf16<<<dim3(3 * CC / 32, CC / 32), dim3(32, 8), 0, stream>>>(
        w_attn, watb, CC, 3 * CC);
    transpose_f32_bf16<<<dim3(CC / 32, CC / 32), dim3(32, 8), 0, stream>>>(
        w_proj, wptb, CC, CC);

    gemm128<0><<<dim3(3 * CC / 128, BT / 128), 256, 0, stream>>>(
        xb, watb, b_attn, qb, kbuf, vtb, nullptr, BT, 3 * CC, CC);

    attn_kernel<<<dim3(8, 2 * NH), 256, 0, stream>>>(qb, kbuf, vtb, yb);

    gemm128<1><<<dim3(CC / 128, BT / 128), 256, 0, stream>>>(
        yb, wptb, b_proj, nullptr, nullptr, nullptr, out, BT, CC, CC);
}

// Round 4
// 141.621 us; speedup vs baseline: 1.3659x; 1.0300x over previous
//
#include <hip/hip_runtime.h>
#include <hip/hip_bf16.h>
#include <stdint.h>

// Problem constants: B=2, T=2048, C=1024, H=16, D=64
#define TT 2048
#define CC 1024
#define NH 16
#define HD 64
#define BT 4096          // B*T rows

typedef float f32x4 __attribute__((ext_vector_type(4)));
typedef __bf16 bf16x8 __attribute__((ext_vector_type(8)));
typedef __bf16 bf16x4 __attribute__((ext_vector_type(4)));

#define MFMA(a, b, c) __builtin_amdgcn_mfma_f32_16x16x32_bf16((a), (b), (c), 0, 0, 0)

__device__ __forceinline__ void gload16(const void* g, void* l) {
    __builtin_amdgcn_global_load_lds(
        (const __attribute__((address_space(1))) void*)g,
        (__attribute__((address_space(3))) void*)l,
        16, 0, 0);
}

// ---------------- fp32 -> bf16 convert (no transpose) ----------------
__global__ __launch_bounds__(256) void conv_f32_bf16(
    const float* __restrict__ in, __bf16* __restrict__ out, int n4) {
    int i = blockIdx.x * blockDim.x + threadIdx.x;
    int stride = gridDim.x * blockDim.x;
    for (; i < n4; i += stride) {
        float4 v = reinterpret_cast<const float4*>(in)[i];
        bf16x4 o;
        o.x = (__bf16)v.x; o.y = (__bf16)v.y; o.z = (__bf16)v.z; o.w = (__bf16)v.w;
        reinterpret_cast<bf16x4*>(out)[i] = o;
    }
}

// ---------------- fp32 [R][C] -> bf16 [C][R] transpose ----------------
__global__ __launch_bounds__(256) void transpose_f32_bf16(
    const float* __restrict__ in, __bf16* __restrict__ out, int R, int C) {
    __shared__ float tile[32][33];
    int c0 = blockIdx.x * 32, r0 = blockIdx.y * 32;
    int tx = threadIdx.x, ty = threadIdx.y;
#pragma unroll
    for (int j = 0; j < 32; j += 8)
        tile[ty + j][tx] = in[(size_t)(r0 + ty + j) * C + c0 + tx];
    __syncthreads();
#pragma unroll
    for (int j = 0; j < 32; j += 8)
        out[(size_t)(c0 + ty + j) * R + r0 + tx] = (__bf16)tile[tx][ty + j];
}

// ---------------- bf16 MFMA GEMM, 128x128 tile, BK=64 (m97 structure) ----
// C = A[M,K] * Bt[N,K]^T + bias. MODE 0: scatter q/k -> [B,H,T,D] bf16
// (q scaled by 0.125), v -> [B,H,D,T] bf16 (pre-transposed for attention).
// MODE 1: fp32 output [M,N].
template <int MODE>
__global__ __launch_bounds__(256) void gemm128(
    const __bf16* __restrict__ A, const __bf16* __restrict__ Bt,
    const float* __restrict__ bias,
    __bf16* __restrict__ oq, __bf16* __restrict__ ok, __bf16* __restrict__ ov,
    float* __restrict__ of, int M, int N, int K) {
    __shared__ __align__(16) __bf16 As[128 * 64];
    __shared__ __align__(16) __bf16 Bs[128 * 64];
    const int tid = threadIdx.x;
    const int w = tid >> 6, lane = tid & 63;
    const int l15 = lane & 15, lg = lane >> 4;
    const int m0 = blockIdx.y * 128, n0 = blockIdx.x * 128;
    const int wr = w >> 1, wc = w & 1;

    const f32x4 zero4 = {0.f, 0.f, 0.f, 0.f};
    f32x4 acc[4][4];
#pragma unroll
    for (int m = 0; m < 4; ++m)
#pragma unroll
        for (int n = 0; n < 4; ++n) acc[m][n] = zero4;

    const char* Ab = (const char*)A;
    const char* Bb = (const char*)Bt;
    const size_t rowbytes = (size_t)K * 2;

    for (int kt = 0; kt < K; kt += 64) {
#pragma unroll
        for (int j = 0; j < 4; ++j) {
            int base = (w * 4 + j) * 1024;
            int d0 = base + lane * 16;
            int row = d0 >> 7;
            int colb = d0 & 127;
            int scolb = colb ^ ((row & 7) << 4);
            gload16(Ab + (size_t)(m0 + row) * rowbytes + (size_t)kt * 2 + scolb,
                    (char*)As + base);
            gload16(Bb + (size_t)(n0 + row) * rowbytes + (size_t)kt * 2 + scolb,
                    (char*)Bs + base);
        }
        __syncthreads();
#pragma unroll
        for (int kk = 0; kk < 2; ++kk) {
            bf16x8 af[4], bfr[4];
#pragma unroll
            for (int m = 0; m < 4; ++m) {
                int row = wr * 64 + m * 16 + l15;
                int colb = kk * 64 + lg * 16;
                af[m] = *(const bf16x8*)((const char*)As + row * 128 +
                                         (colb ^ ((row & 7) << 4)));
            }
#pragma unroll
            for (int n = 0; n < 4; ++n) {
                int row = wc * 64 + n * 16 + l15;
                int colb = kk * 64 + lg * 16;
                bfr[n] = *(const bf16x8*)((const char*)Bs + row * 128 +
                                          (colb ^ ((row & 7) << 4)));
            }
#pragma unroll
            for (int m = 0; m < 4; ++m)
#pragma unroll
                for (int n = 0; n < 4; ++n)
                    acc[m][n] = MFMA(af[m], bfr[n], acc[m][n]);
        }
        __syncthreads();
    }

    // epilogue. D layout: col = lane&15, row = (lane>>4)*4 + r  [verified m89/m91]
#pragma unroll
    for (int n = 0; n < 4; ++n) {
        int col = n0 + wc * 64 + n * 16 + l15;
        float bs = bias[col];
        if constexpr (MODE == 0) {
            int sec = col >> 10;          // 0=q 1=k 2=v
            int cc = col & 1023;
            int h = cc >> 6, d = cc & 63;
            if (sec == 2) {
                // V transposed: [B,H,D,T], pack 4 consecutive t per store
#pragma unroll
                for (int m = 0; m < 4; ++m) {
                    int rowb = m0 + wr * 64 + m * 16 + lg * 4;
                    int bb = rowb >> 11, t = rowb & 2047;
                    bf16x4 pk;
#pragma unroll
                    for (int r = 0; r < 4; ++r) pk[r] = (__bf16)(acc[m][n][r] + bs);
                    *(bf16x4*)&ov[((size_t)(bb * NH + h) * HD + d) * TT + t] = pk;
                }
            } else {
                __bf16* dst = (sec == 0) ? oq : ok;
                float mult = (sec == 0) ? 0.125f : 1.0f;
#pragma unroll
                for (int m = 0; m < 4; ++m) {
                    int rowb = m0 + wr * 64 + m * 16 + lg * 4;
#pragma unroll
                    for (int r = 0; r < 4; ++r) {
                        int row = rowb + r;
                        int bb = row >> 11, t = row & 2047;
                        float val = (acc[m][n][r] + bs) * mult;
                        dst[((size_t)(bb * NH + h) * TT + t) * HD + d] = (__bf16)val;
                    }
                }
            }
        } else {
#pragma unroll
            for (int m = 0; m < 4; ++m) {
                int rowb = m0 + wr * 64 + m * 16 + lg * 4;
#pragma unroll
                for (int r = 0; r < 4; ++r) {
                    int row = rowb + r;
                    of[(size_t)row * N + col] = acc[m][n][r] + bs;
                }
            }
        }
    }
}

// ---------------- causal flash attention --------------------------------
// QTILE=64 (4 waves x 16 q-rows), KVBLK=64, paired q-tiles (qt, 31-qt):
// 512 uniform blocks of 33 steps, ~41KB LDS -> 2 blocks/CU.
// q,k: [B,H,T,64] bf16 (q pre-scaled by 0.125). vt: [B,H,64,T] bf16.
// y: [B*T][1024] bf16.
__global__ __launch_bounds__(256) void attn_kernel(
    const __bf16* __restrict__ q, const __bf16* __restrict__ k,
    const __bf16* __restrict__ vt, __bf16* __restrict__ y) {
    __shared__ __align__(16) __bf16 Kb[2][64 * 64];   // [kv][d] 128B rows, XOR swz
    __shared__ __align__(16) __bf16 Vb[2][64 * 64];   // [d][kv] 128B rows, XOR swz
    __shared__ __align__(16) __bf16 Pl[4][16 * 68];   // per-wave [q][k], pad->68

    const int bh = blockIdx.y;
    const int qp = blockIdx.x;                 // 0..15 pair index
    const int tid = threadIdx.x, w = tid >> 6, lane = tid & 63;
    const int l15 = lane & 15, lg = lane >> 4;
    const char* kh = (const char*)(k + (size_t)bh * TT * HD);
    const char* vh = (const char*)(vt + (size_t)bh * HD * TT);
    const __bf16* qh = q + (size_t)bh * TT * HD;
    const int qtA = qp, qtB = 31 - qp;
    const int nA = qtA + 1, ntot = nA + (qtB + 1);   // == 33

    const f32x4 zero4 = {0.f, 0.f, 0.f, 0.f};
    float mrun[4], lrun[4];
    f32x4 oacc[4];
    bf16x8 qf[2];
    int qbw = 0;

    auto stage = [&](int kvb, int buf) {
#pragma unroll
        for (int j = 0; j < 2; ++j) {
            int d0 = ((w * 2 + j) * 64 + lane) * 16;
            int row = d0 >> 7, colb = d0 & 127;
            int scolb = colb ^ ((row & 7) << 4);
            // K tile: rows kv (128B each)
            gload16(kh + (size_t)(kvb + row) * 128 + scolb, (char*)Kb[buf] + d0);
            // V^T tile: rows d (4096B each), cols kv (128B slice)
            gload16(vh + (size_t)row * (TT * 2) + (size_t)kvb * 2 + scolb,
                    (char*)Vb[buf] + d0);
        }
    };

    auto initQ = [&](int qt) {
        qbw = qt * 64 + w * 16;
#pragma unroll
        for (int kk = 0; kk < 2; ++kk)
            qf[kk] = *(const bf16x8*)&qh[(size_t)(qbw + l15) * HD + kk * 32 + lg * 8];
#pragma unroll
        for (int r = 0; r < 4; ++r) { mrun[r] = -1e30f; lrun[r] = 0.f; }
#pragma unroll
        for (int f = 0; f < 4; ++f) oacc[f] = zero4;
    };

    auto writeO = [&]() {
        const int b = bh >> 4, h = bh & 15;
#pragma unroll
        for (int f = 0; f < 4; ++f)
#pragma unroll
            for (int r = 0; r < 4; ++r) {
                int t = qbw + lg * 4 + r;
                float val = oacc[f][r] / lrun[r];
                y[(size_t)(b * TT + t) * CC + h * 64 + f * 16 + l15] = (__bf16)val;
            }
    };

    stage(0, 0);
    initQ(qtA);
    __syncthreads();

    for (int g = 0; g < ntot; ++g) {
        const int cur = g & 1;
        if (g + 1 < ntot)
            stage((g + 1 < nA ? g + 1 : g + 1 - nA) * 64, cur ^ 1);
        const int kb = (g < nA ? g : g - nA) * 64;

        // ---- QK^T ----  (S frag: col=k=lane&15, row=q=(lane>>4)*4+r)
        f32x4 s[4];
#pragma unroll
        for (int kf = 0; kf < 4; ++kf) s[kf] = zero4;
#pragma unroll
        for (int kf = 0; kf < 4; ++kf) {
            int krow = kf * 16 + l15;
            const char* kr = (const char*)Kb[cur] + krow * 128;
            bf16x8 k0 = *(const bf16x8*)(kr + ((lg * 16) ^ ((krow & 7) << 4)));
            bf16x8 k1 = *(const bf16x8*)(kr + ((64 + lg * 16) ^ ((krow & 7) << 4)));
            s[kf] = MFMA(qf[0], k0, s[kf]);
            s[kf] = MFMA(qf[1], k1, s[kf]);
        }
        // mask needed iff max col (kb+63) can exceed the wave's MIN row (qbw).
        // (round-3 bug: compared against max row qbw+15, leaving wave 3 of the
        //  diagonal tile unmasked)
        if (kb + 63 > qbw) {
#pragma unroll
            for (int kf = 0; kf < 4; ++kf)
#pragma unroll
                for (int r = 0; r < 4; ++r) {
                    int col = kb + kf * 16 + l15;
                    int rowq = qbw + lg * 4 + r;
                    if (col > rowq) s[kf][r] = -1e30f;
                }
        }
        // ---- online softmax ----
        float fac[4];
#pragma unroll
        for (int r = 0; r < 4; ++r) {
            float m_ = fmaxf(fmaxf(s[0][r], s[1][r]), fmaxf(s[2][r], s[3][r]));
#pragma unroll
            for (int off = 1; off < 16; off <<= 1)
                m_ = fmaxf(m_, __shfl_xor(m_, off));
            float mn = fmaxf(mrun[r], m_);
            fac[r] = __expf(mrun[r] - mn);
            mrun[r] = mn;
            float ss = 0.f;
#pragma unroll
            for (int kf = 0; kf < 4; ++kf) {
                float p = __expf(s[kf][r] - mn);
                s[kf][r] = p;
                ss += p;
            }
#pragma unroll
            for (int off = 1; off < 16; off <<= 1)
                ss += __shfl_xor(ss, off);
            lrun[r] = lrun[r] * fac[r] + ss;
        }
#pragma unroll
        for (int f = 0; f < 4; ++f)
#pragma unroll
            for (int r = 0; r < 4; ++r) oacc[f][r] *= fac[r];
        // P -> per-wave LDS (conflict-free write pattern: 32 banks, 2 lanes each)
#pragma unroll
        for (int kf = 0; kf < 4; ++kf)
#pragma unroll
            for (int r = 0; r < 4; ++r)
                Pl[w][(lg * 4 + r) * 68 + kf * 16 + l15] = (__bf16)s[kf][r];
        // ---- O += P V ----  (A = P[q][k], B = V[k][d] via Vt[d][k] LDS)
#pragma unroll
        for (int kq = 0; kq < 2; ++kq) {
            bf16x8 pa = *(const bf16x8*)&Pl[w][l15 * 68 + kq * 32 + lg * 8];
#pragma unroll
            for (int f = 0; f < 4; ++f) {
                int vrow = f * 16 + l15;
                bf16x8 vf = *(const bf16x8*)((const char*)Vb[cur] + vrow * 128 +
                                ((kq * 64 + lg * 16) ^ ((vrow & 7) << 4)));
                oacc[f] = MFMA(pa, vf, oacc[f]);
            }
        }
        __syncthreads();
        if (g == nA - 1) { writeO(); initQ(qtB); }
    }
    writeO();
}

extern "C" void kernel_launch(void* const* d_in, const int* in_sizes, int n_in,
                              void* d_out, int out_size, void* d_ws, size_t ws_size,
                              hipStream_t stream) {
    const float* x      = (const float*)d_in[0];
    const float* w_attn = (const float*)d_in[1];
    const float* b_attn = (const float*)d_in[2];
    const float* w_proj = (const float*)d_in[3];
    const float* b_proj = (const float*)d_in[4];
    float* out = (float*)d_out;

    char* ws = (char*)d_ws;
    size_t off = 0;
    auto alloc = [&](size_t bytes) {
        char* p = ws + off;
        off += (bytes + 255) & ~(size_t)255;
        return p;
    };
    __bf16* xb   = (__bf16*)alloc((size_t)BT * CC * 2);
    __bf16* watb = (__bf16*)alloc((size_t)3 * CC * CC * 2);
    __bf16* wptb = (__bf16*)alloc((size_t)CC * CC * 2);
    __bf16* qb   = (__bf16*)alloc((size_t)BT * CC * 2);
    __bf16* kbuf = (__bf16*)alloc((size_t)BT * CC * 2);
    __bf16* vtb  = (__bf16*)alloc((size_t)BT * CC * 2);  // [B,H,D,T]
    __bf16* yb   = (__bf16*)alloc((size_t)BT * CC * 2);

    conv_f32_bf16<<<1024, 256, 0, stream>>>(x, xb, BT * CC / 4);
    transpose_f32_bf16<<<dim3(3 * CC / 32, CC / 32), dim3(32, 8), 0, stream>>>(
        w_attn, watb, CC, 3 * CC);
    transpose_f32_bf16<<<dim3(CC / 32, CC / 32), dim3(32, 8), 0, stream>>>(
        w_proj, wptb, CC, CC);

    gemm128<0><<<dim3(3 * CC / 128, BT / 128), 256, 0, stream>>>(
        xb, watb, b_attn, qb, kbuf, vtb, nullptr, BT, 3 * CC, CC);

    attn_kernel<<<dim3(16, 2 * NH), 256, 0, stream>>>(qb, kbuf, vtb, yb);

    gemm128<1><<<dim3(CC / 128, BT / 128), 256, 0, stream>>>(
        yb, wptb, b_proj, nullptr, nullptr, nullptr, out, BT, CC, CC);
}